// Round 4
// baseline (1207.175 us; speedup 1.0000x reference)
//
#include <hip/hip_runtime.h>

#define N_NODES 100000
#define N_EDGES 1600000

// ---------------------------------------------------------------------------
__global__ void hist_kernel(const int* __restrict__ dst, int* __restrict__ counts, int E) {
    int e = blockIdx.x * blockDim.x + threadIdx.x;
    if (e < E) atomicAdd(&counts[dst[e]], 1);
}

__global__ void dinv_kernel(const int* __restrict__ counts, float* __restrict__ dinv, int n) {
    int i = blockIdx.x * blockDim.x + threadIdx.x;
    if (i < n) dinv[i] = rsqrtf((float)counts[i] + 1.0f);
}

// --- 3-kernel exclusive scan of counts[n] -> rowptr[n] ----------------------
__global__ void scan1_kernel(const int* __restrict__ counts, int* __restrict__ rowptr,
                             int* __restrict__ bsums, int n) {
    __shared__ int s[256];
    int i = blockIdx.x * 256 + threadIdx.x;
    int v = (i < n) ? counts[i] : 0;
    s[threadIdx.x] = v;
    __syncthreads();
    for (int off = 1; off < 256; off <<= 1) {
        int t = (threadIdx.x >= off) ? s[threadIdx.x - off] : 0;
        __syncthreads();
        s[threadIdx.x] += t;
        __syncthreads();
    }
    if (i < n) rowptr[i] = s[threadIdx.x] - v;
    if (threadIdx.x == 255) bsums[blockIdx.x] = s[255];
}

__global__ void scan2_kernel(int* __restrict__ bsums, int nb) {
    __shared__ int s[512];
    int t = threadIdx.x;
    int v = (t < nb) ? bsums[t] : 0;
    s[t] = v;
    __syncthreads();
    for (int off = 1; off < 512; off <<= 1) {
        int u = (t >= off) ? s[t - off] : 0;
        __syncthreads();
        s[t] += u;
        __syncthreads();
    }
    if (t < nb) bsums[t] = s[t] - v;
}

__global__ void scan3_kernel(int* __restrict__ rowptr, const int* __restrict__ bsums, int n) {
    int i = blockIdx.x * 256 + threadIdx.x;
    if (i < n) rowptr[i] += bsums[blockIdx.x];
}

// --- scatter edges into CSR order; rowptr becomes row-end offsets -----------
__global__ void scatter_kernel(const int* __restrict__ src, const int* __restrict__ dst,
                               const float* __restrict__ dinv, int* __restrict__ rowptr,
                               int2* __restrict__ edges, int E) {
    int e = blockIdx.x * blockDim.x + threadIdx.x;
    if (e >= E) return;
    int s = src[e];
    int d = dst[e];
    float w = dinv[s] * dinv[d];
    int pos = atomicAdd(&rowptr[d], 1);
    edges[pos] = make_int2(s, __float_as_int(w));
}

// ---------------------------------------------------------------------------
// LDS-tiled GEMM, 4x4 register blocking. 256 threads/block.
// Each thread: 4 rows x 4 cols. Per k-chunk(4): 8 ds_read_b128 + 64 FMA.
template <int FIN, int FOUT>
__global__ void gemm_tiled(const float* __restrict__ in, const float* __restrict__ W,
                           float* __restrict__ out, int n) {
    constexpr int CG = FOUT / 4;          // col groups
    constexpr int RG = 256 / CG;          // row groups
    constexpr int TR = RG * 4;            // tile rows (64 or 128)
    constexpr int LDA = FIN + 4;          // pad: breaks same-bank row starts
    __shared__ float sIn[TR * LDA];
    __shared__ float sW[FIN * FOUT];

    for (int i = threadIdx.x; i < FIN * FOUT / 4; i += 256)
        ((float4*)sW)[i] = ((const float4*)W)[i];

    int r0 = blockIdx.x * TR;
    for (int i = threadIdx.x; i < TR * FIN / 4; i += 256) {
        int rr = i / (FIN / 4);
        int cc = i % (FIN / 4);
        int gr = r0 + rr;
        float4 v = (gr < n) ? ((const float4*)in)[(size_t)gr * (FIN / 4) + cc]
                            : make_float4(0.f, 0.f, 0.f, 0.f);
        *(float4*)&sIn[rr * LDA + cc * 4] = v;
    }
    __syncthreads();

    int tc = threadIdx.x % CG;
    int tr = threadIdx.x / CG;
    int rbase = tr * 4, cbase = tc * 4;
    float acc[4][4] = {};

#pragma unroll
    for (int k = 0; k < FIN; k += 4) {
        float4 a[4], b[4];
#pragma unroll
        for (int i = 0; i < 4; i++) a[i] = *(float4*)&sIn[(rbase + i) * LDA + k];
#pragma unroll
        for (int kk = 0; kk < 4; kk++) b[kk] = *(float4*)&sW[(k + kk) * FOUT + cbase];
#pragma unroll
        for (int i = 0; i < 4; i++) {
            acc[i][0] += a[i].x * b[0].x + a[i].y * b[1].x + a[i].z * b[2].x + a[i].w * b[3].x;
            acc[i][1] += a[i].x * b[0].y + a[i].y * b[1].y + a[i].z * b[2].y + a[i].w * b[3].y;
            acc[i][2] += a[i].x * b[0].z + a[i].y * b[1].z + a[i].z * b[2].z + a[i].w * b[3].z;
            acc[i][3] += a[i].x * b[0].w + a[i].y * b[1].w + a[i].z * b[2].w + a[i].w * b[3].w;
        }
    }

#pragma unroll
    for (int i = 0; i < 4; i++) {
        int gr = r0 + rbase + i;
        if (gr < n)
            *(float4*)&out[(size_t)gr * FOUT + cbase] =
                make_float4(acc[i][0], acc[i][1], acc[i][2], acc[i][3]);
    }
}

// simple GEMM for the tiny 32->2 layer
template <int FIN, int FOUT>
__global__ void gemm_kernel(const float* __restrict__ in, const float* __restrict__ W,
                            float* __restrict__ out, int n) {
    __shared__ float sW[FIN * FOUT];
    for (int i = threadIdx.x; i < FIN * FOUT; i += blockDim.x) sW[i] = W[i];
    __syncthreads();
    constexpr int ROWS = 256 / FOUT;
    int r = blockIdx.x * ROWS + threadIdx.x / FOUT;
    int c = threadIdx.x % FOUT;
    if (r >= n) return;
    float acc = 0.f;
#pragma unroll
    for (int k = 0; k < FIN; k++) acc += in[r * FIN + k] * sW[k * FOUT + c];
    out[r * FOUT + c] = acc;
}

// ---------------------------------------------------------------------------
// Gather-side aggregation, zero atomics, finalize fused, 8x unrolled
// (8 independent gather chains in flight per wave).
template <int F, bool RELU>
__global__ void agg_kernel(const int2* __restrict__ edges, const int* __restrict__ rowend,
                           const float* __restrict__ dinv, const float* __restrict__ h,
                           const float* __restrict__ b, float* __restrict__ out, int n) {
    int g = (blockIdx.x * blockDim.x + threadIdx.x) / F;   // node
    int lane = threadIdx.x % F;                            // feature
    if (g >= n) return;
    int end = rowend[g];
    int j = (g == 0) ? 0 : rowend[g - 1];
    float di = dinv[g];
    float hs = h[(size_t)g * F + lane];

    float acc0 = 0.f, acc1 = 0.f, acc2 = 0.f, acc3 = 0.f;
    float acc4 = 0.f, acc5 = 0.f, acc6 = 0.f, acc7 = 0.f;
    for (; j + 8 <= end; j += 8) {
        int2 e0 = edges[j];
        int2 e1 = edges[j + 1];
        int2 e2 = edges[j + 2];
        int2 e3 = edges[j + 3];
        int2 e4 = edges[j + 4];
        int2 e5 = edges[j + 5];
        int2 e6 = edges[j + 6];
        int2 e7 = edges[j + 7];
        float h0 = h[(size_t)e0.x * F + lane];
        float h1 = h[(size_t)e1.x * F + lane];
        float h2 = h[(size_t)e2.x * F + lane];
        float h3 = h[(size_t)e3.x * F + lane];
        float h4 = h[(size_t)e4.x * F + lane];
        float h5 = h[(size_t)e5.x * F + lane];
        float h6 = h[(size_t)e6.x * F + lane];
        float h7 = h[(size_t)e7.x * F + lane];
        acc0 += __int_as_float(e0.y) * h0;
        acc1 += __int_as_float(e1.y) * h1;
        acc2 += __int_as_float(e2.y) * h2;
        acc3 += __int_as_float(e3.y) * h3;
        acc4 += __int_as_float(e4.y) * h4;
        acc5 += __int_as_float(e5.y) * h5;
        acc6 += __int_as_float(e6.y) * h6;
        acc7 += __int_as_float(e7.y) * h7;
    }
    for (; j + 2 <= end; j += 2) {
        int2 e0 = edges[j];
        int2 e1 = edges[j + 1];
        float h0 = h[(size_t)e0.x * F + lane];
        float h1 = h[(size_t)e1.x * F + lane];
        acc0 += __int_as_float(e0.y) * h0;
        acc1 += __int_as_float(e1.y) * h1;
    }
    if (j < end) {
        int2 e = edges[j];
        acc2 += __int_as_float(e.y) * h[(size_t)e.x * F + lane];
    }
    float acc = ((acc0 + acc1) + (acc2 + acc3)) + ((acc4 + acc5) + (acc6 + acc7));
    float v = acc + di * di * hs + b[lane];
    out[(size_t)g * F + lane] = RELU ? fmaxf(v, 0.f) : v;
}

// ---------------------------------------------------------------------------
extern "C" void kernel_launch(void* const* d_in, const int* in_sizes, int n_in,
                              void* d_out, int out_size, void* d_ws, size_t ws_size,
                              hipStream_t stream) {
    const float* x  = (const float*)d_in[0];
    const int* ei   = (const int*)d_in[1];
    const float* W1 = (const float*)d_in[2];
    const float* b1 = (const float*)d_in[3];
    const float* W2 = (const float*)d_in[4];
    const float* b2 = (const float*)d_in[5];
    const float* W3 = (const float*)d_in[6];
    const float* b3 = (const float*)d_in[7];
    float* out = (float*)d_out;

    const int N = N_NODES;
    const int E = N_EDGES;
    const int* src = ei;
    const int* dst = ei + E;

    char* p = (char*)d_ws;
    int*   counts = (int*)p;              p += ((size_t)N * 4 + 15) / 16 * 16;
    int*   rowptr = (int*)p;              p += ((size_t)N * 4 + 15) / 16 * 16;
    int*   bsums  = (int*)p;              p += 512 * 4;
    float* dinv   = (float*)p;            p += ((size_t)N * 4 + 15) / 16 * 16;
    int2*  edges  = (int2*)p;             p += (size_t)E * 8;
    float* A      = (float*)p;            p += (size_t)N * 64 * 4;
    float* B      = (float*)p;

    const int T = 256;
    const int NB = (N + 255) / 256;

    // --- build CSR + dinv ---
    hipMemsetAsync(counts, 0, (size_t)N * sizeof(int), stream);
    hist_kernel<<<(E + T - 1) / T, T, 0, stream>>>(dst, counts, E);
    dinv_kernel<<<NB, T, 0, stream>>>(counts, dinv, N);
    scan1_kernel<<<NB, T, 0, stream>>>(counts, rowptr, bsums, N);
    scan2_kernel<<<1, 512, 0, stream>>>(bsums, NB);
    scan3_kernel<<<NB, T, 0, stream>>>(rowptr, bsums, N);
    scatter_kernel<<<(E + T - 1) / T, T, 0, stream>>>(src, dst, dinv, rowptr, edges, E);

    // --- layer 1: x @ W1 -> A; aggregate+relu -> B ---
    gemm_tiled<64, 64><<<(N + 63) / 64, T, 0, stream>>>(x, W1, A, N);
    agg_kernel<64, true><<<(N * 64 + T - 1) / T, T, 0, stream>>>(edges, rowptr, dinv, A, b1, B, N);

    // --- layer 2: B @ W2 -> A[N,32]; aggregate+relu -> B ---
    gemm_tiled<64, 32><<<(N + 127) / 128, T, 0, stream>>>(B, W2, A, N);
    agg_kernel<32, true><<<(N * 32 + T - 1) / T, T, 0, stream>>>(edges, rowptr, dinv, A, b2, B, N);

    // --- layer 3: B @ W3 -> A[N,2]; aggregate -> d_out ---
    gemm_kernel<32, 2><<<(N + 127) / 128, T, 0, stream>>>(B, W3, A, N);
    agg_kernel<2, false><<<(N * 2 + T - 1) / T, T, 0, stream>>>(edges, rowptr, dinv, A, b3, out, N);
}

// Round 5
// 396.789 us; speedup vs baseline: 3.0424x; 3.0424x over previous
//
#include <hip/hip_runtime.h>

#define N_NODES 100000
#define N_EDGES 1600000

// ---------------------------------------------------------------------------
__global__ void hist_kernel(const int* __restrict__ dst, int* __restrict__ counts, int E) {
    int e = blockIdx.x * blockDim.x + threadIdx.x;
    if (e < E) atomicAdd(&counts[dst[e]], 1);
}

__global__ void dinv_kernel(const int* __restrict__ counts, float* __restrict__ dinv, int n) {
    int i = blockIdx.x * blockDim.x + threadIdx.x;
    if (i < n) dinv[i] = rsqrtf((float)counts[i] + 1.0f);
}

// --- 3-kernel exclusive scan of counts[n] -> rowptr[n] ----------------------
__global__ void scan1_kernel(const int* __restrict__ counts, int* __restrict__ rowptr,
                             int* __restrict__ bsums, int n) {
    __shared__ int s[256];
    int i = blockIdx.x * 256 + threadIdx.x;
    int v = (i < n) ? counts[i] : 0;
    s[threadIdx.x] = v;
    __syncthreads();
    for (int off = 1; off < 256; off <<= 1) {
        int t = (threadIdx.x >= off) ? s[threadIdx.x - off] : 0;
        __syncthreads();
        s[threadIdx.x] += t;
        __syncthreads();
    }
    if (i < n) rowptr[i] = s[threadIdx.x] - v;
    if (threadIdx.x == 255) bsums[blockIdx.x] = s[255];
}

__global__ void scan2_kernel(int* __restrict__ bsums, int nb) {
    __shared__ int s[512];
    int t = threadIdx.x;
    int v = (t < nb) ? bsums[t] : 0;
    s[t] = v;
    __syncthreads();
    for (int off = 1; off < 512; off <<= 1) {
        int u = (t >= off) ? s[t - off] : 0;
        __syncthreads();
        s[t] += u;
        __syncthreads();
    }
    if (t < nb) bsums[t] = s[t] - v;
}

__global__ void scan3_kernel(int* __restrict__ rowptr, const int* __restrict__ bsums, int n) {
    int i = blockIdx.x * 256 + threadIdx.x;
    if (i < n) rowptr[i] += bsums[blockIdx.x];
}

// --- scatter edges into CSR order; rowptr becomes row-end offsets -----------
__global__ void scatter_kernel(const int* __restrict__ src, const int* __restrict__ dst,
                               const float* __restrict__ dinv, int* __restrict__ rowptr,
                               int2* __restrict__ edges, int E) {
    int e = blockIdx.x * blockDim.x + threadIdx.x;
    if (e >= E) return;
    int s = src[e];
    int d = dst[e];
    float w = dinv[s] * dinv[d];
    int pos = atomicAdd(&rowptr[d], 1);
    edges[pos] = make_int2(s, __float_as_int(w));
}

// ---------------------------------------------------------------------------
// LDS-tiled GEMM, 4x4 register blocking. 256 threads/block.
// __launch_bounds__(256,2): allow up to ~256 VGPRs (round-4 spilled at 64).
// #pragma unroll 2: cap hoisted LDS staging regs (full unroll spilled 4KB/thr).
template <int FIN, int FOUT>
__global__ __launch_bounds__(256, 2)
void gemm_tiled(const float* __restrict__ in, const float* __restrict__ W,
                float* __restrict__ out, int n) {
    constexpr int CG = FOUT / 4;          // col groups
    constexpr int RG = 256 / CG;          // row groups
    constexpr int TR = RG * 4;            // tile rows (64 or 128)
    constexpr int LDA = FIN + 4;
    __shared__ float sIn[TR * LDA];
    __shared__ float sW[FIN * FOUT];

    for (int i = threadIdx.x; i < FIN * FOUT / 4; i += 256)
        ((float4*)sW)[i] = ((const float4*)W)[i];

    int r0 = blockIdx.x * TR;
    for (int i = threadIdx.x; i < TR * FIN / 4; i += 256) {
        int rr = i / (FIN / 4);
        int cc = i % (FIN / 4);
        int gr = r0 + rr;
        float4 v = (gr < n) ? ((const float4*)in)[(size_t)gr * (FIN / 4) + cc]
                            : make_float4(0.f, 0.f, 0.f, 0.f);
        *(float4*)&sIn[rr * LDA + cc * 4] = v;
    }
    __syncthreads();

    int tc = threadIdx.x % CG;
    int tr = threadIdx.x / CG;
    int rbase = tr * 4, cbase = tc * 4;
    float acc[4][4] = {};

#pragma unroll 2
    for (int k = 0; k < FIN; k += 4) {
        float4 a[4], b[4];
#pragma unroll
        for (int i = 0; i < 4; i++) a[i] = *(float4*)&sIn[(rbase + i) * LDA + k];
#pragma unroll
        for (int kk = 0; kk < 4; kk++) b[kk] = *(float4*)&sW[(k + kk) * FOUT + cbase];
#pragma unroll
        for (int i = 0; i < 4; i++) {
            acc[i][0] += a[i].x * b[0].x + a[i].y * b[1].x + a[i].z * b[2].x + a[i].w * b[3].x;
            acc[i][1] += a[i].x * b[0].y + a[i].y * b[1].y + a[i].z * b[2].y + a[i].w * b[3].y;
            acc[i][2] += a[i].x * b[0].z + a[i].y * b[1].z + a[i].z * b[2].z + a[i].w * b[3].z;
            acc[i][3] += a[i].x * b[0].w + a[i].y * b[1].w + a[i].z * b[2].w + a[i].w * b[3].w;
        }
    }

#pragma unroll
    for (int i = 0; i < 4; i++) {
        int gr = r0 + rbase + i;
        if (gr < n)
            *(float4*)&out[(size_t)gr * FOUT + cbase] =
                make_float4(acc[i][0], acc[i][1], acc[i][2], acc[i][3]);
    }
}

// simple GEMM for the tiny 32->2 layer
template <int FIN, int FOUT>
__global__ void gemm_kernel(const float* __restrict__ in, const float* __restrict__ W,
                            float* __restrict__ out, int n) {
    __shared__ float sW[FIN * FOUT];
    for (int i = threadIdx.x; i < FIN * FOUT; i += blockDim.x) sW[i] = W[i];
    __syncthreads();
    constexpr int ROWS = 256 / FOUT;
    int r = blockIdx.x * ROWS + threadIdx.x / FOUT;
    int c = threadIdx.x % FOUT;
    if (r >= n) return;
    float acc = 0.f;
#pragma unroll
    for (int k = 0; k < FIN; k++) acc += in[r * FIN + k] * sW[k * FOUT + c];
    out[r * FOUT + c] = acc;
}

// ---------------------------------------------------------------------------
// Gather-side aggregation, zero atomics, finalize fused, 8x unrolled
// (8 independent gather chains in flight per wave).
template <int F, bool RELU>
__global__ void agg_kernel(const int2* __restrict__ edges, const int* __restrict__ rowend,
                           const float* __restrict__ dinv, const float* __restrict__ h,
                           const float* __restrict__ b, float* __restrict__ out, int n) {
    int g = (blockIdx.x * blockDim.x + threadIdx.x) / F;   // node
    int lane = threadIdx.x % F;                            // feature
    if (g >= n) return;
    int end = rowend[g];
    int j = (g == 0) ? 0 : rowend[g - 1];
    float di = dinv[g];
    float hs = h[(size_t)g * F + lane];

    float acc0 = 0.f, acc1 = 0.f, acc2 = 0.f, acc3 = 0.f;
    float acc4 = 0.f, acc5 = 0.f, acc6 = 0.f, acc7 = 0.f;
    for (; j + 8 <= end; j += 8) {
        int2 e0 = edges[j];
        int2 e1 = edges[j + 1];
        int2 e2 = edges[j + 2];
        int2 e3 = edges[j + 3];
        int2 e4 = edges[j + 4];
        int2 e5 = edges[j + 5];
        int2 e6 = edges[j + 6];
        int2 e7 = edges[j + 7];
        float h0 = h[(size_t)e0.x * F + lane];
        float h1 = h[(size_t)e1.x * F + lane];
        float h2 = h[(size_t)e2.x * F + lane];
        float h3 = h[(size_t)e3.x * F + lane];
        float h4 = h[(size_t)e4.x * F + lane];
        float h5 = h[(size_t)e5.x * F + lane];
        float h6 = h[(size_t)e6.x * F + lane];
        float h7 = h[(size_t)e7.x * F + lane];
        acc0 += __int_as_float(e0.y) * h0;
        acc1 += __int_as_float(e1.y) * h1;
        acc2 += __int_as_float(e2.y) * h2;
        acc3 += __int_as_float(e3.y) * h3;
        acc4 += __int_as_float(e4.y) * h4;
        acc5 += __int_as_float(e5.y) * h5;
        acc6 += __int_as_float(e6.y) * h6;
        acc7 += __int_as_float(e7.y) * h7;
    }
    for (; j + 2 <= end; j += 2) {
        int2 e0 = edges[j];
        int2 e1 = edges[j + 1];
        float h0 = h[(size_t)e0.x * F + lane];
        float h1 = h[(size_t)e1.x * F + lane];
        acc0 += __int_as_float(e0.y) * h0;
        acc1 += __int_as_float(e1.y) * h1;
    }
    if (j < end) {
        int2 e = edges[j];
        acc2 += __int_as_float(e.y) * h[(size_t)e.x * F + lane];
    }
    float acc = ((acc0 + acc1) + (acc2 + acc3)) + ((acc4 + acc5) + (acc6 + acc7));
    float v = acc + di * di * hs + b[lane];
    out[(size_t)g * F + lane] = RELU ? fmaxf(v, 0.f) : v;
}

// ---------------------------------------------------------------------------
extern "C" void kernel_launch(void* const* d_in, const int* in_sizes, int n_in,
                              void* d_out, int out_size, void* d_ws, size_t ws_size,
                              hipStream_t stream) {
    const float* x  = (const float*)d_in[0];
    const int* ei   = (const int*)d_in[1];
    const float* W1 = (const float*)d_in[2];
    const float* b1 = (const float*)d_in[3];
    const float* W2 = (const float*)d_in[4];
    const float* b2 = (const float*)d_in[5];
    const float* W3 = (const float*)d_in[6];
    const float* b3 = (const float*)d_in[7];
    float* out = (float*)d_out;

    const int N = N_NODES;
    const int E = N_EDGES;
    const int* src = ei;
    const int* dst = ei + E;

    char* p = (char*)d_ws;
    int*   counts = (int*)p;              p += ((size_t)N * 4 + 15) / 16 * 16;
    int*   rowptr = (int*)p;              p += ((size_t)N * 4 + 15) / 16 * 16;
    int*   bsums  = (int*)p;              p += 512 * 4;
    float* dinv   = (float*)p;            p += ((size_t)N * 4 + 15) / 16 * 16;
    int2*  edges  = (int2*)p;             p += (size_t)E * 8;
    float* A      = (float*)p;            p += (size_t)N * 64 * 4;
    float* B      = (float*)p;

    const int T = 256;
    const int NB = (N + 255) / 256;

    // --- build CSR + dinv ---
    hipMemsetAsync(counts, 0, (size_t)N * sizeof(int), stream);
    hist_kernel<<<(E + T - 1) / T, T, 0, stream>>>(dst, counts, E);
    dinv_kernel<<<NB, T, 0, stream>>>(counts, dinv, N);
    scan1_kernel<<<NB, T, 0, stream>>>(counts, rowptr, bsums, N);
    scan2_kernel<<<1, 512, 0, stream>>>(bsums, NB);
    scan3_kernel<<<NB, T, 0, stream>>>(rowptr, bsums, N);
    scatter_kernel<<<(E + T - 1) / T, T, 0, stream>>>(src, dst, dinv, rowptr, edges, E);

    // --- layer 1: x @ W1 -> A; aggregate+relu -> B ---
    gemm_tiled<64, 64><<<(N + 63) / 64, T, 0, stream>>>(x, W1, A, N);
    agg_kernel<64, true><<<(N * 64 + T - 1) / T, T, 0, stream>>>(edges, rowptr, dinv, A, b1, B, N);

    // --- layer 2: B @ W2 -> A[N,32]; aggregate+relu -> B ---
    gemm_tiled<64, 32><<<(N + 127) / 128, T, 0, stream>>>(B, W2, A, N);
    agg_kernel<32, true><<<(N * 32 + T - 1) / T, T, 0, stream>>>(edges, rowptr, dinv, A, b2, B, N);

    // --- layer 3: B @ W3 -> A[N,2]; aggregate -> d_out ---
    gemm_kernel<32, 2><<<(N + 127) / 128, T, 0, stream>>>(B, W3, A, N);
    agg_kernel<2, false><<<(N * 2 + T - 1) / T, T, 0, stream>>>(edges, rowptr, dinv, A, b3, out, N);
}